// Round 2
// baseline (789.324 us; speedup 1.0000x reference)
//
#include <hip/hip_runtime.h>

#define N_ACTC 80
#define M_CONC 85
#define NZC 84
#define MGC 169
#define RHO_C 10.0f
#define SIGMA_C 1e-6f
#define PEN_C 1000.0f
#define ITERS_C 200

// One sample per block. Register-resident A (col+row chunks) and K^{-1} (via
// in-register SPD sweep). LDS only for vectors/partials (~12KB).
// launch_bounds(256,2): ~256-VGPR budget so the ~110-reg working set stays in
// arch VGPRs (at (256,3) the allocator split arrays into AGPR/scratch: 68 VGPRs,
// 8x slowdown).
__launch_bounds__(256, 2)
__global__ void qp_admm_kernel(const float* __restrict__ xraw,
                               const float* __restrict__ Ag,
                               const float* __restrict__ bg,
                               const float* __restrict__ lowg,
                               float* __restrict__ outp) {
  const int s = blockIdx.x;
  const int t = threadIdx.x;
  const float* A = Ag + (size_t)s * (M_CONC * N_ACTC);

  __shared__ __align__(16) float xr[80];
  __shared__ __align__(16) float rinv[96];
  __shared__ __align__(16) float slab[16 * 84];   // 16 rows, pitch 84 (cols 80..83 zero)
  __shared__ __align__(16) float u_lds[176];
  __shared__ __align__(16) float rhs_lds[84];
  __shared__ __align__(16) float z_lds[84];
  __shared__ __align__(16) float psumA[252];
  __shared__ __align__(16) float psumB[252];
  __shared__ __align__(16) float psumC[256];
  __shared__ __align__(16) float rkbuf[2][84];
  __shared__ __align__(16) float psq[256];

  const int iB = t % 84, pB = t / 84;   // K row iB, col run [pB*28, pB*28+28)  (t<252)
  const int iA = t % 80, pA = t / 80;   // A^T u: output col iA, row chunk pA*29 (t<240)
  const int rC = t % 85, pC = t / 85;   // A z: row rC, col run pC*28            (t<255)

  if (t < 80) xr[t] = xraw[s * 80 + t];
  if (t < 84) z_lds[t] = 0.f;
  if (t < 176) u_lds[t] = 0.f;
  if (t >= 85 && t < 96) rinv[t] = 0.f;

  float kreg[28];   // first used as AtA accumulator, then K, then -K^{-1}
#pragma unroll
  for (int jj = 0; jj < 28; ++jj) kreg[jj] = 0.f;
  float creg_c[28];
#pragma unroll
  for (int jj = 0; jj < 28; ++jj) creg_c[jj] = 0.f;

  // ---- slab loop: row norms, normalized A slabs, AtA accumulation, row cache
  for (int sl = 0; sl < 6; ++sl) {
    const int r0 = sl * 16;
    for (int e = t; e < 16 * 80; e += 256) {
      int rl = e / 80;
      int c = e - rl * 80;
      int r = r0 + rl;
      slab[rl * 84 + c] = (r < M_CONC) ? A[r * 80 + c] : 0.f;
    }
    if (t < 64) slab[(t >> 2) * 84 + 80 + (t & 3)] = 0.f;
    __syncthreads();
    {
      int rl = t >> 4, p = t & 15;
      float acc = 0.f;
#pragma unroll
      for (int c = 0; c < 5; ++c) {
        float v = slab[rl * 84 + p * 5 + c];
        acc += v * v;
      }
      psq[t] = acc;
    }
    __syncthreads();
    if (t < 16 && (r0 + t) < M_CONC) {
      float n2 = 0.f;
#pragma unroll
      for (int p = 0; p < 16; ++p) n2 += psq[t * 16 + p];
      float rn = fmaxf(sqrtf(n2), 1e-12f);
      rinv[r0 + t] = 1.0f / rn;
    }
    __syncthreads();
    for (int e = t; e < 16 * 80; e += 256) {
      int rl = e / 80;
      int c = e - rl * 80;
      slab[rl * 84 + c] *= rinv[r0 + rl];   // rows >=85 scale by 0 (stay 0)
    }
    __syncthreads();
    // AtA accumulation into registers (rank-16 update)
    if (t < 252 && iB < 80) {
      for (int rl = 0; rl < 16; ++rl) {
        float ai = slab[rl * 84 + iB];
#pragma unroll
        for (int jj = 0; jj < 28; ++jj)
          kreg[jj] += ai * slab[rl * 84 + pB * 28 + jj];
      }
    }
    // phase-C row cache (whole chunk comes from one slab -> static reg indices)
    if (t < 255 && rC >= r0 && rC < r0 + 16) {
      int rl = rC - r0;
#pragma unroll
      for (int jj = 0; jj < 28; ++jj) creg_c[jj] = slab[rl * 84 + pC * 28 + jj];
    }
    __syncthreads();   // NOTE: after last slab, slab[] holds normalized rows 80..84 at locals 0..4
  }

  // ---- phase-A column cache straight from global (coalesced: lanes consecutive in iA)
  float creg_a[29];
  if (t < 240) {
#pragma unroll
    for (int rr = 0; rr < 29; ++rr) {
      int r = pA * 29 + rr;
      creg_a[rr] = (r < M_CONC) ? A[r * 80 + iA] * rinv[r] : 0.f;
    }
  } else {
#pragma unroll
    for (int rr = 0; rr < 29; ++rr) creg_a[rr] = 0.f;
  }

  // ---- assemble K = RHO*G^T G + diag(pdiag + SIGMA) in place (kreg holds AtA)
  if (t < 252) {
#pragma unroll
    for (int jj = 0; jj < 28; ++jj) {
      int j = pB * 28 + jj;
      float v;
      if (iB < 80) {
        v = (j < 80)
              ? (RHO_C * kreg[jj] + ((j == iB) ? (RHO_C + 1.0f + SIGMA_C) : 0.f))
              : (-RHO_C * slab[(j - 80 + 1) * 84 + iB]);   // -RHO*A_soft[s][i], soft rows at locals 1..4
      } else {
        int ss = iB - 80;
        v = (j < 80)
              ? (-RHO_C * slab[(ss + 1) * 84 + j])
              : ((j - 80 == ss) ? (2.f * RHO_C + 2.f * PEN_C + SIGMA_C) : 0.f);
      }
      kreg[jj] = v;
    }
  }

  if (t < 252 && iB == 0) {
#pragma unroll
    for (int jj = 0; jj < 28; ++jj) rkbuf[0][pB * 28 + jj] = kreg[jj];
  }
  __syncthreads();

  // ---- SPD sweep (Gauss-Jordan) in registers; final kreg = -K^{-1}
  for (int k = 0; k < NZC; ++k) {
    const float* rk = rkbuf[k & 1];
    float dinv = 1.0f / rk[k];
    if (t < 252) {
      float t1 = rk[iB] * dinv;
      bool rowk = (iB == k);
      int jfix = k - pB * 28;
#pragma unroll
      for (int jj = 0; jj < 28; ++jj) {
        float rkj = rk[pB * 28 + jj];
        float gen = kreg[jj] - t1 * rkj;
        float val = rowk ? ((jj == jfix) ? -dinv : rkj * dinv)
                         : ((jj == jfix) ? t1 : gen);
        kreg[jj] = val;
      }
      if (k < NZC - 1 && iB == k + 1) {
#pragma unroll
        for (int jj = 0; jj < 28; ++jj) rkbuf[(k + 1) & 1][pB * 28 + jj] = kreg[jj];
      }
    }
    __syncthreads();
  }

  // ---- per-thread constraint state
  float yor_r = 0.f, h_r = 0.f;
  if (t < MGC) {
    if (t < 85) h_r = bg[s * 85 + t] * rinv[t];
    else if (t < 89) h_r = 0.f;
    else h_r = -lowg[s * 80 + (t - 89)];
  }
  __syncthreads();

  // ---- 200 ADMM iterations
  for (int it = 0; it < ITERS_C; ++it) {
    // phase A: partials of A^T u
    if (t < 240) {
      float acc = 0.f;
#pragma unroll
      for (int rr = 0; rr < 29; ++rr) acc += creg_a[rr] * u_lds[pA * 29 + rr];
      psumA[pA * 84 + iA] = acc;
    }
    __syncthreads();
    // combine-1: rhs = SIGMA z - q + G^T u
    if (t < 84) {
      float rhsv;
      if (t < 80)
        rhsv = psumA[t] + psumA[84 + t] + psumA[168 + t] + xr[t] + SIGMA_C * z_lds[t] - u_lds[89 + t];
      else {
        int ss = t - 80;
        rhsv = SIGMA_C * z_lds[t] - u_lds[81 + ss] - u_lds[85 + ss];
      }
      rhs_lds[t] = rhsv;
    }
    __syncthreads();
    // phase B: partials of (-K^{-1}) rhs
    if (t < 252) {
      float acc = 0.f;
#pragma unroll
      for (int jj = 0; jj < 28; ++jj) acc += kreg[jj] * rhs_lds[pB * 28 + jj];
      psumB[pB * 84 + iB] = acc;
    }
    __syncthreads();
    // combine-2: z = K^{-1} rhs  (negate the sweep result)
    if (t < 84) z_lds[t] = -(psumB[t] + psumB[84 + t] + psumB[168 + t]);
    __syncthreads();
    // phase C: partials of A x
    if (t < 255) {
      float acc = 0.f;
#pragma unroll
      for (int jj = 0; jj < 28; ++jj) acc += creg_c[jj] * z_lds[pC * 28 + jj];
      psumC[pC * 85 + rC] = acc;
    }
    __syncthreads();
    // update: Gz, v, w=min(v,h), u = RHO(2w - v), yor = v - w
    if (t < MGC) {
      float gz;
      if (t < 85) {
        gz = psumC[t] + psumC[85 + t] + psumC[170 + t];
        if (t >= 81) gz -= z_lds[80 + (t - 81)];
      } else if (t < 89) {
        gz = -z_lds[80 + (t - 85)];
      } else {
        gz = -z_lds[t - 89];
      }
      float v = gz + yor_r;
      float w = fminf(v, h_r);
      u_lds[t] = RHO_C * (2.f * w - v);
      yor_r = v - w;
    }
    __syncthreads();
  }

  if (t < 80) outp[s * 80 + t] = z_lds[t];
}

extern "C" void kernel_launch(void* const* d_in, const int* in_sizes, int n_in,
                              void* d_out, int out_size, void* d_ws, size_t ws_size,
                              hipStream_t stream) {
  const float* xraw = (const float*)d_in[0];
  const float* Ag   = (const float*)d_in[1];
  const float* bg   = (const float*)d_in[2];
  const float* lowg = (const float*)d_in[3];
  float* outp = (float*)d_out;
  const int B = in_sizes[0] / N_ACTC;
  qp_admm_kernel<<<B, 256, 0, stream>>>(xraw, Ag, bg, lowg, outp);
}

// Round 4
// 679.572 us; speedup vs baseline: 1.1615x; 1.1615x over previous
//
#include <hip/hip_runtime.h>

#define N_ACTC 80
#define M_CONC 85
#define NZC 84
#define MGC 169
#define RHO_C 10.0f
#define SIGMA_C 1e-6f
#define PEN_C 1000.0f
#define ITERS_C 200
#define PITCH 85   // nA pitch: 85%32=21, gcd(21,32)=1 -> row-indexed reads conflict-free

// One sample per block, 256 threads. Normalized A lives in LDS at pitch 85
// (cols 80..84 zeroed so phase C / AtA can read 28-wide runs unguarded);
// only the -K^{-1} row-chunk (28 floats) lives in registers. LDS ~34.8KB ->
// 4 blocks/CU resident, all 1024 blocks in one round; barrier latency hidden
// by cross-block TLP.
__launch_bounds__(256, 4)
__global__ void qp_admm_kernel(const float* __restrict__ xraw,
                               const float* __restrict__ Ag,
                               const float* __restrict__ bg,
                               const float* __restrict__ lowg,
                               float* __restrict__ outp) {
  const int s = blockIdx.x;
  const int t = threadIdx.x;
  const float* A = Ag + (size_t)s * (M_CONC * N_ACTC);

  __shared__ __align__(16) float nA[85 * PITCH];  // normalized A, pitch 85
  __shared__ __align__(16) float xr[80];
  __shared__ __align__(16) float rinv[96];
  __shared__ __align__(16) float u_lds[176];
  __shared__ __align__(16) float rhs_lds[84];
  __shared__ __align__(16) float z_lds[84];
  __shared__ __align__(16) float psumA[240];
  __shared__ __align__(16) float psumB[252];
  __shared__ __align__(16) float psumC[256];
  __shared__ __align__(16) float rkbuf[2][84];
  __shared__ __align__(16) float psq[256];

  const int iB = t % 84, pB = t / 84;   // K row iB, col run [pB*28, pB*28+28)  (t<252)
  const int iA = t % 80, pA = t / 80;   // A^T u: output col iA, row chunk pA*29 (t<240)
  const int rC = t % 85, pC = t / 85;   // A z: row rC, col run pC*28            (t<255)

  if (t < 80) xr[t] = xraw[s * 80 + t];
  if (t < 84) z_lds[t] = 0.f;
  if (t < 176) u_lds[t] = 0.f;

  // ---- load A into LDS (coalesced global reads) + zero pad cols 80..84
  for (int e = t; e < 85 * 80; e += 256) {
    int r = e / 80, c = e - r * 80;
    nA[r * PITCH + c] = A[e];
  }
  for (int e = t; e < 85 * 5; e += 256) {
    int r = e / 5;
    nA[r * PITCH + 80 + (e - r * 5)] = 0.f;
  }
  __syncthreads();

  // ---- row norms: 255 threads, 3 partials per row
  if (t < 255) {
    int r = t / 3, p = t - 3 * r;
    int c0 = p * 27;
    int len = (p == 2) ? 26 : 27;
    float acc = 0.f;
    for (int k = 0; k < len; ++k) {
      float v = nA[r * PITCH + c0 + k];
      acc += v * v;
    }
    psq[t] = acc;
  }
  __syncthreads();
  if (t < 85) {
    float n2 = psq[3 * t] + psq[3 * t + 1] + psq[3 * t + 2];
    rinv[t] = 1.0f / fmaxf(sqrtf(n2), 1e-12f);
  }
  __syncthreads();
  // ---- normalize in place (pad cols stay zero)
  for (int e = t; e < 85 * 80; e += 256) {
    int r = e / 80, c = e - r * 80;
    nA[r * PITCH + c] *= rinv[r];
  }
  __syncthreads();

  // ---- AtA accumulation into kreg (x-rows only; pad cols give 0 for j>=80)
  float kreg[28];   // AtA acc -> K -> -K^{-1}
#pragma unroll
  for (int jj = 0; jj < 28; ++jj) kreg[jj] = 0.f;
  if (t < 252 && iB < 80) {
    for (int r = 0; r < 85; ++r) {
      float ai = nA[r * PITCH + iB];
#pragma unroll
      for (int jj = 0; jj < 28; ++jj)
        kreg[jj] += ai * nA[r * PITCH + pB * 28 + jj];
    }
  }

  // ---- assemble K = RHO*G^T G + diag(pdiag + SIGMA) in place
  // soft rows are constraint rows 81..84 (N_HARD=81)
  if (t < 252) {
#pragma unroll
    for (int jj = 0; jj < 28; ++jj) {
      int j = pB * 28 + jj;
      float v;
      if (iB < 80) {
        v = (j < 80)
              ? (RHO_C * kreg[jj] + ((j == iB) ? (RHO_C + 1.0f + SIGMA_C) : 0.f))
              : (-RHO_C * nA[(81 + (j - 80)) * PITCH + iB]);
      } else {
        int ss = iB - 80;
        v = (j < 80)
              ? (-RHO_C * nA[(81 + ss) * PITCH + j])
              : ((j - 80 == ss) ? (2.f * RHO_C + 2.f * PEN_C + SIGMA_C) : 0.f);
      }
      kreg[jj] = v;
    }
  }

  if (t < 252 && iB == 0) {
#pragma unroll
    for (int jj = 0; jj < 28; ++jj) rkbuf[0][pB * 28 + jj] = kreg[jj];
  }
  __syncthreads();

  // ---- SPD sweep (Gauss-Jordan) in registers; final kreg = -K^{-1}
  for (int k = 0; k < NZC; ++k) {
    const float* rk = rkbuf[k & 1];
    float dinv = 1.0f / rk[k];
    if (t < 252) {
      float t1 = rk[iB] * dinv;
      bool rowk = (iB == k);
      int jfix = k - pB * 28;
#pragma unroll
      for (int jj = 0; jj < 28; ++jj) {
        float rkj = rk[pB * 28 + jj];
        float gen = kreg[jj] - t1 * rkj;
        float val = rowk ? ((jj == jfix) ? -dinv : rkj * dinv)
                         : ((jj == jfix) ? t1 : gen);
        kreg[jj] = val;
      }
      if (k < NZC - 1 && iB == k + 1) {
#pragma unroll
        for (int jj = 0; jj < 28; ++jj) rkbuf[(k + 1) & 1][pB * 28 + jj] = kreg[jj];
      }
    }
    __syncthreads();
  }

  // ---- per-thread constraint state
  float yor_r = 0.f, h_r = 0.f;
  if (t < MGC) {
    if (t < 85) h_r = bg[s * 85 + t] * rinv[t];
    else if (t < 89) h_r = 0.f;
    else h_r = -lowg[s * 80 + (t - 89)];
  }
  __syncthreads();

  // ---- 200 ADMM iterations
  for (int it = 0; it < ITERS_C; ++it) {
    // phase A: partials of A^T u   (A columns from LDS, lane-consecutive iA)
    if (t < 240) {
      float acc = 0.f;
#pragma unroll
      for (int rr = 0; rr < 29; ++rr) {
        int r = pA * 29 + rr;
        if (r < 85) acc += nA[r * PITCH + iA] * u_lds[r];
      }
      psumA[pA * 80 + iA] = acc;
    }
    __syncthreads();
    // combine-1: rhs = SIGMA z - q + G^T u
    if (t < 84) {
      float rhsv;
      if (t < 80)
        rhsv = psumA[t] + psumA[80 + t] + psumA[160 + t] + xr[t] + SIGMA_C * z_lds[t] - u_lds[89 + t];
      else {
        int ss = t - 80;
        rhsv = SIGMA_C * z_lds[t] - u_lds[81 + ss] - u_lds[85 + ss];
      }
      rhs_lds[t] = rhsv;
    }
    __syncthreads();
    // phase B: partials of (-K^{-1}) rhs  (kreg in registers, rhs broadcast)
    if (t < 252) {
      float acc = 0.f;
#pragma unroll
      for (int jj = 0; jj < 28; ++jj) acc += kreg[jj] * rhs_lds[pB * 28 + jj];
      psumB[pB * 84 + iB] = acc;
    }
    __syncthreads();
    // combine-2: z = K^{-1} rhs  (negate the sweep result)
    if (t < 84) z_lds[t] = -(psumB[t] + psumB[84 + t] + psumB[168 + t]);
    __syncthreads();
    // phase C: partials of A z   (pitch-85 rows: lanes hit all 32 banks, 2-way)
    if (t < 255) {
      float acc = 0.f;
#pragma unroll
      for (int jj = 0; jj < 28; ++jj)
        acc += nA[rC * PITCH + pC * 28 + jj] * z_lds[pC * 28 + jj];
      psumC[pC * 85 + rC] = acc;
    }
    __syncthreads();
    // update: Gz, v, w=min(v,h), u = RHO(2w - v), yor = v - w
    if (t < MGC) {
      float gz;
      if (t < 85) {
        gz = psumC[t] + psumC[85 + t] + psumC[170 + t];
        if (t >= 81) gz -= z_lds[80 + (t - 81)];
      } else if (t < 89) {
        gz = -z_lds[80 + (t - 85)];
      } else {
        gz = -z_lds[t - 89];
      }
      float v = gz + yor_r;
      float w = fminf(v, h_r);
      u_lds[t] = RHO_C * (2.f * w - v);
      yor_r = v - w;
    }
    __syncthreads();
  }

  if (t < 80) outp[s * 80 + t] = z_lds[t];
}

extern "C" void kernel_launch(void* const* d_in, const int* in_sizes, int n_in,
                              void* d_out, int out_size, void* d_ws, size_t ws_size,
                              hipStream_t stream) {
  const float* xraw = (const float*)d_in[0];
  const float* Ag   = (const float*)d_in[1];
  const float* bg   = (const float*)d_in[2];
  const float* lowg = (const float*)d_in[3];
  float* outp = (float*)d_out;
  const int B = in_sizes[0] / N_ACTC;
  qp_admm_kernel<<<B, 256, 0, stream>>>(xraw, Ag, bg, lowg, outp);
}

// Round 5
// 621.177 us; speedup vs baseline: 1.2707x; 1.0940x over previous
//
#include <hip/hip_runtime.h>

#define N_ACTC 80
#define M_CONC 85
#define NZC 84
#define MGC 169
#define RHO_C 10.0f
#define SIGMA_C 1e-6f
#define PEN_C 1000.0f
#define ITERS_C 200
#define PITCH 84   // 16B-aligned rows (84*4=336=21*16); 20*r mod 32 spreads b128 starts evenly

// One sample per block, 256 threads. Normalized A in LDS at pitch 84 (cols
// 80..83 zero). All contiguous LDS reads vectorized to ds_read_b128 (matrix
// rows, z/rhs/u vectors); only phase-A column reads stay b32 (same LDS-unit
// cycles as a transposed-copy b128 scheme, without halving occupancy).
// LDS ~34KB -> 4 blocks/CU.
__launch_bounds__(256, 4)
__global__ void qp_admm_kernel(const float* __restrict__ xraw,
                               const float* __restrict__ Ag,
                               const float* __restrict__ bg,
                               const float* __restrict__ lowg,
                               float* __restrict__ outp) {
  const int s = blockIdx.x;
  const int t = threadIdx.x;
  const float* A = Ag + (size_t)s * (M_CONC * N_ACTC);

  __shared__ __align__(16) float nA[85 * PITCH];
  __shared__ __align__(16) float xr[80];
  __shared__ __align__(16) float rinv[88];
  __shared__ __align__(16) float u_lds[176];
  __shared__ __align__(16) float rhs_lds[84];
  __shared__ __align__(16) float z_lds[84];
  __shared__ __align__(16) float psumA[240];
  __shared__ __align__(16) float psumB[252];
  __shared__ __align__(16) float psumC[256];
  __shared__ __align__(16) float rkbuf[2][84];   // row 1 at byte 336 (16B-aligned)
  __shared__ __align__(16) float psq[256];

  const int iB = t % 84, pB = t / 84;   // K row iB, col run [pB*28, +28)   (t<252)
  const int iA = t % 80, pA = t / 80;   // A^T u: col iA, row chunk {0,32,64} (t<240)
  const int rC = t % 85, pC = t / 85;   // A z: row rC, col run pC*28        (t<255)

  if (t < 80) xr[t] = xraw[s * 80 + t];
  if (t < 84) z_lds[t] = 0.f;
  if (t < 176) u_lds[t] = 0.f;

  // ---- load A into LDS + zero pad cols 80..83
  for (int e = t; e < 85 * PITCH; e += 256) {
    int r = e / PITCH, c = e - r * PITCH;
    nA[e] = (c < 80) ? A[r * 80 + c] : 0.f;
  }
  __syncthreads();

  // ---- row norms: 255 threads, 3 partials per row
  if (t < 255) {
    int r = t / 3, p = t - 3 * r;
    int c0 = p * 27;
    int len = (p == 2) ? 26 : 27;
    float acc = 0.f;
    for (int k = 0; k < len; ++k) {
      float v = nA[r * PITCH + c0 + k];
      acc += v * v;
    }
    psq[t] = acc;
  }
  __syncthreads();
  if (t < 85) {
    float n2 = psq[3 * t] + psq[3 * t + 1] + psq[3 * t + 2];
    rinv[t] = 1.0f / fmaxf(sqrtf(n2), 1e-12f);
  }
  __syncthreads();
  for (int e = t; e < 85 * PITCH; e += 256) nA[e] *= rinv[e / PITCH];
  __syncthreads();

  // ---- AtA accumulation into kreg (x-rows only; pad cols give 0 for j>=80)
  float kreg[28];   // AtA acc -> K -> -K^{-1}
#pragma unroll
  for (int jj = 0; jj < 28; ++jj) kreg[jj] = 0.f;
  if (t < 252 && iB < 80) {
    for (int r = 0; r < 85; ++r) {
      float ai = nA[r * PITCH + iB];
      const float4* rv = reinterpret_cast<const float4*>(&nA[r * PITCH + pB * 28]);
#pragma unroll
      for (int q = 0; q < 7; ++q) {
        float4 v = rv[q];
        kreg[4 * q + 0] += ai * v.x;
        kreg[4 * q + 1] += ai * v.y;
        kreg[4 * q + 2] += ai * v.z;
        kreg[4 * q + 3] += ai * v.w;
      }
    }
  }

  // ---- assemble K = RHO*G^T G + diag(pdiag + SIGMA) in place
  if (t < 252) {
#pragma unroll
    for (int jj = 0; jj < 28; ++jj) {
      int j = pB * 28 + jj;
      float v;
      if (iB < 80) {
        v = (j < 80)
              ? (RHO_C * kreg[jj] + ((j == iB) ? (RHO_C + 1.0f + SIGMA_C) : 0.f))
              : (-RHO_C * nA[(81 + (j - 80)) * PITCH + iB]);
      } else {
        int ss = iB - 80;
        v = (j < 80)
              ? (-RHO_C * nA[(81 + ss) * PITCH + j])
              : ((j - 80 == ss) ? (2.f * RHO_C + 2.f * PEN_C + SIGMA_C) : 0.f);
      }
      kreg[jj] = v;
    }
  }

  if (t < 252 && iB == 0) {
#pragma unroll
    for (int jj = 0; jj < 28; ++jj) rkbuf[0][pB * 28 + jj] = kreg[jj];
  }
  __syncthreads();

  // ---- SPD sweep (Gauss-Jordan) in registers; final kreg = -K^{-1}
  for (int k = 0; k < NZC; ++k) {
    const float* rk = rkbuf[k & 1];
    const float4* rkv = reinterpret_cast<const float4*>(rk);
    float dinv = 1.0f / rk[k];
    if (t < 252) {
      float t1 = rk[iB] * dinv;
      bool rowk = (iB == k);
      int jfix = k - pB * 28;
      float rkrow[28];
#pragma unroll
      for (int q = 0; q < 7; ++q) {
        float4 v = rkv[pB * 7 + q];
        rkrow[4 * q + 0] = v.x; rkrow[4 * q + 1] = v.y;
        rkrow[4 * q + 2] = v.z; rkrow[4 * q + 3] = v.w;
      }
#pragma unroll
      for (int jj = 0; jj < 28; ++jj) {
        float rkj = rkrow[jj];
        float gen = kreg[jj] - t1 * rkj;
        float val = rowk ? ((jj == jfix) ? -dinv : rkj * dinv)
                         : ((jj == jfix) ? t1 : gen);
        kreg[jj] = val;
      }
      if (k < NZC - 1 && iB == k + 1) {
        float4* wv = reinterpret_cast<float4*>(&rkbuf[(k + 1) & 1][pB * 28]);
#pragma unroll
        for (int q = 0; q < 7; ++q)
          wv[q] = make_float4(kreg[4 * q + 0], kreg[4 * q + 1],
                              kreg[4 * q + 2], kreg[4 * q + 3]);
      }
    }
    __syncthreads();
  }

  // ---- per-thread constraint state
  float yor_r = 0.f, h_r = 0.f;
  if (t < MGC) {
    if (t < 85) h_r = bg[s * 85 + t] * rinv[t];
    else if (t < 89) h_r = 0.f;
    else h_r = -lowg[s * 80 + (t - 89)];
  }
  __syncthreads();

  // ---- 200 ADMM iterations
  for (int it = 0; it < ITERS_C; ++it) {
    // phase A: partials of A^T u (matrix cols b32 conflict-free, u as b128 broadcast)
    if (t < 240) {
      float a0 = 0.f, a1 = 0.f;
      if (pA < 2) {
        const int r0 = pA * 32;
#pragma unroll
        for (int q = 0; q < 8; ++q) {
          float4 uv = *reinterpret_cast<const float4*>(&u_lds[r0 + 4 * q]);
          a0 += nA[(r0 + 4 * q + 0) * PITCH + iA] * uv.x;
          a1 += nA[(r0 + 4 * q + 1) * PITCH + iA] * uv.y;
          a0 += nA[(r0 + 4 * q + 2) * PITCH + iA] * uv.z;
          a1 += nA[(r0 + 4 * q + 3) * PITCH + iA] * uv.w;
        }
      } else {
#pragma unroll
        for (int q = 0; q < 5; ++q) {
          float4 uv = *reinterpret_cast<const float4*>(&u_lds[64 + 4 * q]);
          a0 += nA[(64 + 4 * q + 0) * PITCH + iA] * uv.x;
          a1 += nA[(64 + 4 * q + 1) * PITCH + iA] * uv.y;
          a0 += nA[(64 + 4 * q + 2) * PITCH + iA] * uv.z;
          a1 += nA[(64 + 4 * q + 3) * PITCH + iA] * uv.w;
        }
        a0 += nA[84 * PITCH + iA] * u_lds[84];
      }
      psumA[pA * 80 + iA] = a0 + a1;
    }
    __syncthreads();
    // combine-1: rhs = SIGMA z - q + G^T u
    if (t < 84) {
      float rhsv;
      if (t < 80)
        rhsv = psumA[t] + psumA[80 + t] + psumA[160 + t] + xr[t] + SIGMA_C * z_lds[t] - u_lds[89 + t];
      else {
        int ss = t - 80;
        rhsv = SIGMA_C * z_lds[t] - u_lds[81 + ss] - u_lds[85 + ss];
      }
      rhs_lds[t] = rhsv;
    }
    __syncthreads();
    // phase B: partials of (-K^{-1}) rhs (kreg in regs, rhs b128 broadcast)
    if (t < 252) {
      const float4* rc = reinterpret_cast<const float4*>(&rhs_lds[pB * 28]);
      float a0 = 0.f, a1 = 0.f, a2 = 0.f, a3 = 0.f;
#pragma unroll
      for (int q = 0; q < 7; ++q) {
        float4 rv = rc[q];
        a0 += kreg[4 * q + 0] * rv.x;
        a1 += kreg[4 * q + 1] * rv.y;
        a2 += kreg[4 * q + 2] * rv.z;
        a3 += kreg[4 * q + 3] * rv.w;
      }
      psumB[pB * 84 + iB] = (a0 + a1) + (a2 + a3);
    }
    __syncthreads();
    // combine-2: z = K^{-1} rhs (negate the sweep result)
    if (t < 84) z_lds[t] = -(psumB[t] + psumB[84 + t] + psumB[168 + t]);
    __syncthreads();
    // phase C: partials of A z (matrix rows + z both b128)
    if (t < 255) {
      const float4* av = reinterpret_cast<const float4*>(&nA[rC * PITCH + pC * 28]);
      const float4* zv4 = reinterpret_cast<const float4*>(&z_lds[pC * 28]);
      float a0 = 0.f, a1 = 0.f, a2 = 0.f, a3 = 0.f;
#pragma unroll
      for (int q = 0; q < 7; ++q) {
        float4 av_ = av[q];
        float4 zv_ = zv4[q];
        a0 += av_.x * zv_.x;
        a1 += av_.y * zv_.y;
        a2 += av_.z * zv_.z;
        a3 += av_.w * zv_.w;
      }
      psumC[pC * 85 + rC] = (a0 + a1) + (a2 + a3);
    }
    __syncthreads();
    // update: Gz, v, w=min(v,h), u = RHO(2w - v), yor = v - w
    if (t < MGC) {
      float gz;
      if (t < 85) {
        gz = psumC[t] + psumC[85 + t] + psumC[170 + t];
        if (t >= 81) gz -= z_lds[80 + (t - 81)];
      } else if (t < 89) {
        gz = -z_lds[80 + (t - 85)];
      } else {
        gz = -z_lds[t - 89];
      }
      float v = gz + yor_r;
      float w = fminf(v, h_r);
      u_lds[t] = RHO_C * (2.f * w - v);
      yor_r = v - w;
    }
    __syncthreads();
  }

  if (t < 80) outp[s * 80 + t] = z_lds[t];
}

extern "C" void kernel_launch(void* const* d_in, const int* in_sizes, int n_in,
                              void* d_out, int out_size, void* d_ws, size_t ws_size,
                              hipStream_t stream) {
  const float* xraw = (const float*)d_in[0];
  const float* Ag   = (const float*)d_in[1];
  const float* bg   = (const float*)d_in[2];
  const float* lowg = (const float*)d_in[3];
  float* outp = (float*)d_out;
  const int B = in_sizes[0] / N_ACTC;
  qp_admm_kernel<<<B, 256, 0, stream>>>(xraw, Ag, bg, lowg, outp);
}

// Round 6
// 500.055 us; speedup vs baseline: 1.5785x; 1.2422x over previous
//
#include <hip/hip_runtime.h>

#define N_ACTC 80
#define M_CONC 85
#define NZC 84
#define MGC 169
#define RHO_C 10.0f
#define SIGMA_C 1e-6f
#define PEN_C 1000.0f
#define ITERS_C 200
#define PITCH 84   // 16B-aligned rows (84*4=336); row starts spread over banks

// One sample per block, 256 threads, 4 blocks/CU (LDS ~34KB, VGPR<=128).
// LDS-instruction-issue is the measured bottleneck (R4/R5): so
//  - phase A (A^T u): A^T chunk in REGISTERS (at[32], zero-padded rows>=85),
//    u read as wave-broadcast b128 -> near-zero LDS cost.
//  - phase B (K^{-1} rhs): K^{-1} rows in registers, rhs b128 broadcast.
//  - phase C (A z): A rows from LDS as per-lane b128 (near LDS floor).
__launch_bounds__(256, 4)
__global__ void qp_admm_kernel(const float* __restrict__ xraw,
                               const float* __restrict__ Ag,
                               const float* __restrict__ bg,
                               const float* __restrict__ lowg,
                               float* __restrict__ outp) {
  const int s = blockIdx.x;
  const int t = threadIdx.x;
  const float* A = Ag + (size_t)s * (M_CONC * N_ACTC);

  __shared__ __align__(16) float nA[85 * PITCH];
  __shared__ __align__(16) float xr[80];
  __shared__ __align__(16) float rinv[88];
  __shared__ __align__(16) float u_lds[176];
  __shared__ __align__(16) float rhs_lds[84];
  __shared__ __align__(16) float z_lds[84];
  __shared__ __align__(16) float psumA[240];
  __shared__ __align__(16) float psumB[252];
  __shared__ __align__(16) float psumC[256];
  __shared__ __align__(16) float rkbuf[2][84];
  __shared__ __align__(16) float psq[256];

  const int iB = t % 84, pB = t / 84;   // K row iB, col run [pB*28, +28)   (t<252)
  const int iA = t % 80, pA = t / 80;   // A^T u: col iA, row chunk [pA*32, +32)
  const int rC = t % 85, pC = t / 85;   // A z: row rC, col run pC*28        (t<255)

  if (t < 80) xr[t] = xraw[s * 80 + t];
  if (t < 84) z_lds[t] = 0.f;
  if (t < 176) u_lds[t] = 0.f;

  // ---- load A into LDS + zero pad cols 80..83
  for (int e = t; e < 85 * PITCH; e += 256) {
    int r = e / PITCH, c = e - r * PITCH;
    nA[e] = (c < 80) ? A[r * 80 + c] : 0.f;
  }
  __syncthreads();

  // ---- row norms: 255 threads, 3 partials per row
  if (t < 255) {
    int r = t / 3, p = t - 3 * r;
    int c0 = p * 27;
    int len = (p == 2) ? 26 : 27;
    float acc = 0.f;
    for (int k = 0; k < len; ++k) {
      float v = nA[r * PITCH + c0 + k];
      acc += v * v;
    }
    psq[t] = acc;
  }
  __syncthreads();
  if (t < 85) {
    float n2 = psq[3 * t] + psq[3 * t + 1] + psq[3 * t + 2];
    rinv[t] = 1.0f / fmaxf(sqrtf(n2), 1e-12f);
  }
  __syncthreads();
  for (int e = t; e < 85 * PITCH; e += 256) nA[e] *= rinv[e / PITCH];
  __syncthreads();

  // ---- A^T chunk into registers (zero-padded: rows >=85 and t>=240 all land 0)
  float at[32];
  {
    const int r0 = pA * 32;
#pragma unroll
    for (int rr = 0; rr < 32; ++rr) {
      int r = r0 + rr;
      at[rr] = (r < 85) ? nA[r * PITCH + iA] : 0.f;
    }
  }

  // ---- AtA accumulation into kreg (x-rows only; pad cols give 0 for j>=80)
  float kreg[28];   // AtA acc -> K -> -K^{-1}
#pragma unroll
  for (int jj = 0; jj < 28; ++jj) kreg[jj] = 0.f;
  if (t < 252 && iB < 80) {
    for (int r = 0; r < 85; ++r) {
      float ai = nA[r * PITCH + iB];
      const float4* rv = reinterpret_cast<const float4*>(&nA[r * PITCH + pB * 28]);
#pragma unroll
      for (int q = 0; q < 7; ++q) {
        float4 v = rv[q];
        kreg[4 * q + 0] += ai * v.x;
        kreg[4 * q + 1] += ai * v.y;
        kreg[4 * q + 2] += ai * v.z;
        kreg[4 * q + 3] += ai * v.w;
      }
    }
  }

  // ---- assemble K = RHO*G^T G + diag(pdiag + SIGMA) in place
  if (t < 252) {
#pragma unroll
    for (int jj = 0; jj < 28; ++jj) {
      int j = pB * 28 + jj;
      float v;
      if (iB < 80) {
        v = (j < 80)
              ? (RHO_C * kreg[jj] + ((j == iB) ? (RHO_C + 1.0f + SIGMA_C) : 0.f))
              : (-RHO_C * nA[(81 + (j - 80)) * PITCH + iB]);
      } else {
        int ss = iB - 80;
        v = (j < 80)
              ? (-RHO_C * nA[(81 + ss) * PITCH + j])
              : ((j - 80 == ss) ? (2.f * RHO_C + 2.f * PEN_C + SIGMA_C) : 0.f);
      }
      kreg[jj] = v;
    }
  }

  if (t < 252 && iB == 0) {
#pragma unroll
    for (int jj = 0; jj < 28; ++jj) rkbuf[0][pB * 28 + jj] = kreg[jj];
  }
  __syncthreads();

  // ---- SPD sweep (Gauss-Jordan) in registers; final kreg = -K^{-1}
  for (int k = 0; k < NZC; ++k) {
    const float* rk = rkbuf[k & 1];
    const float4* rkv = reinterpret_cast<const float4*>(rk);
    float dinv = 1.0f / rk[k];
    if (t < 252) {
      float t1 = rk[iB] * dinv;
      bool rowk = (iB == k);
      int jfix = k - pB * 28;
      float rkrow[28];
#pragma unroll
      for (int q = 0; q < 7; ++q) {
        float4 v = rkv[pB * 7 + q];
        rkrow[4 * q + 0] = v.x; rkrow[4 * q + 1] = v.y;
        rkrow[4 * q + 2] = v.z; rkrow[4 * q + 3] = v.w;
      }
#pragma unroll
      for (int jj = 0; jj < 28; ++jj) {
        float rkj = rkrow[jj];
        float gen = kreg[jj] - t1 * rkj;
        float val = rowk ? ((jj == jfix) ? -dinv : rkj * dinv)
                         : ((jj == jfix) ? t1 : gen);
        kreg[jj] = val;
      }
      if (k < NZC - 1 && iB == k + 1) {
        float4* wv = reinterpret_cast<float4*>(&rkbuf[(k + 1) & 1][pB * 28]);
#pragma unroll
        for (int q = 0; q < 7; ++q)
          wv[q] = make_float4(kreg[4 * q + 0], kreg[4 * q + 1],
                              kreg[4 * q + 2], kreg[4 * q + 3]);
      }
    }
    __syncthreads();
  }

  // ---- per-thread constraint state
  float yor_r = 0.f, h_r = 0.f;
  if (t < MGC) {
    if (t < 85) h_r = bg[s * 85 + t] * rinv[t];
    else if (t < 89) h_r = 0.f;
    else h_r = -lowg[s * 80 + (t - 89)];
  }
  __syncthreads();

  // ---- 200 ADMM iterations
  for (int it = 0; it < ITERS_C; ++it) {
    // phase A: A^T u from registers; u as b128 broadcasts (reads u[64..95]
    // for pA=2 are real u values times zero-padded at[] -> harmless)
    {
      const float4* ub = reinterpret_cast<const float4*>(&u_lds[pA * 32]);
      float a0 = 0.f, a1 = 0.f, a2 = 0.f, a3 = 0.f;
#pragma unroll
      for (int q = 0; q < 8; ++q) {
        float4 uv = ub[q];
        a0 += at[4 * q + 0] * uv.x;
        a1 += at[4 * q + 1] * uv.y;
        a2 += at[4 * q + 2] * uv.z;
        a3 += at[4 * q + 3] * uv.w;
      }
      if (t < 240) psumA[pA * 80 + iA] = (a0 + a1) + (a2 + a3);
    }
    __syncthreads();
    // combine-1: rhs = SIGMA z - q + G^T u
    if (t < 84) {
      float rhsv;
      if (t < 80)
        rhsv = psumA[t] + psumA[80 + t] + psumA[160 + t] + xr[t] + SIGMA_C * z_lds[t] - u_lds[89 + t];
      else {
        int ss = t - 80;
        rhsv = SIGMA_C * z_lds[t] - u_lds[81 + ss] - u_lds[85 + ss];
      }
      rhs_lds[t] = rhsv;
    }
    __syncthreads();
    // phase B: partials of (-K^{-1}) rhs (kreg in regs, rhs b128 broadcast)
    if (t < 252) {
      const float4* rc = reinterpret_cast<const float4*>(&rhs_lds[pB * 28]);
      float a0 = 0.f, a1 = 0.f, a2 = 0.f, a3 = 0.f;
#pragma unroll
      for (int q = 0; q < 7; ++q) {
        float4 rv = rc[q];
        a0 += kreg[4 * q + 0] * rv.x;
        a1 += kreg[4 * q + 1] * rv.y;
        a2 += kreg[4 * q + 2] * rv.z;
        a3 += kreg[4 * q + 3] * rv.w;
      }
      psumB[pB * 84 + iB] = (a0 + a1) + (a2 + a3);
    }
    __syncthreads();
    // combine-2: z = K^{-1} rhs (negate the sweep result)
    if (t < 84) z_lds[t] = -(psumB[t] + psumB[84 + t] + psumB[168 + t]);
    __syncthreads();
    // phase C: partials of A z (matrix rows + z both b128)
    if (t < 255) {
      const float4* av = reinterpret_cast<const float4*>(&nA[rC * PITCH + pC * 28]);
      const float4* zv4 = reinterpret_cast<const float4*>(&z_lds[pC * 28]);
      float a0 = 0.f, a1 = 0.f, a2 = 0.f, a3 = 0.f;
#pragma unroll
      for (int q = 0; q < 7; ++q) {
        float4 av_ = av[q];
        float4 zv_ = zv4[q];
        a0 += av_.x * zv_.x;
        a1 += av_.y * zv_.y;
        a2 += av_.z * zv_.z;
        a3 += av_.w * zv_.w;
      }
      psumC[pC * 85 + rC] = (a0 + a1) + (a2 + a3);
    }
    __syncthreads();
    // update: Gz, v, w=min(v,h), u = RHO(2w - v), yor = v - w
    if (t < MGC) {
      float gz;
      if (t < 85) {
        gz = psumC[t] + psumC[85 + t] + psumC[170 + t];
        if (t >= 81) gz -= z_lds[80 + (t - 81)];
      } else if (t < 89) {
        gz = -z_lds[80 + (t - 85)];
      } else {
        gz = -z_lds[t - 89];
      }
      float v = gz + yor_r;
      float w = fminf(v, h_r);
      u_lds[t] = RHO_C * (2.f * w - v);
      yor_r = v - w;
    }
    __syncthreads();
  }

  if (t < 80) outp[s * 80 + t] = z_lds[t];
}

extern "C" void kernel_launch(void* const* d_in, const int* in_sizes, int n_in,
                              void* d_out, int out_size, void* d_ws, size_t ws_size,
                              hipStream_t stream) {
  const float* xraw = (const float*)d_in[0];
  const float* Ag   = (const float*)d_in[1];
  const float* bg   = (const float*)d_in[2];
  const float* lowg = (const float*)d_in[3];
  float* outp = (float*)d_out;
  const int B = in_sizes[0] / N_ACTC;
  qp_admm_kernel<<<B, 256, 0, stream>>>(xraw, Ag, bg, lowg, outp);
}

// Round 7
// 455.555 us; speedup vs baseline: 1.7327x; 1.0977x over previous
//
#include <hip/hip_runtime.h>

#define N_ACTC 80
#define M_CONC 85
#define NZC 84
#define MGC 169
#define RHO_C 10.0f
#define SIGMA_C 1e-6f
#define PEN_C 1000.0f
#define ITERS_C 200
#define PITCH 84   // 16B-aligned rows (84*4=336); row starts spread over banks

typedef float f32x2 __attribute__((ext_vector_type(2)));
// D = S0*S1 + D  (packed 2xfp32, VOP3P). Scalar v_fma_f32 is half-rate vs this.
#define PKFMA(acc, a, b) \
  asm("v_pk_fma_f32 %0, %1, %2, %0" : "+v"(acc) : "v"(a), "v"(b))

// One sample per block, 256 threads, 4 blocks/CU (LDS ~34KB).
// R6 showed VALU-issue bound (58% busy, LDS ~2.3k cyc/iter/CU): this round
// packs all matvec FMAs into v_pk_fma_f32 (2 fp32 FMA/inst) — phase A from
// register-resident A^T chunks, phase B from register-resident -K^{-1} rows,
// phase C from LDS b128 row reads.
__launch_bounds__(256, 4)
__global__ void qp_admm_kernel(const float* __restrict__ xraw,
                               const float* __restrict__ Ag,
                               const float* __restrict__ bg,
                               const float* __restrict__ lowg,
                               float* __restrict__ outp) {
  const int s = blockIdx.x;
  const int t = threadIdx.x;
  const float* A = Ag + (size_t)s * (M_CONC * N_ACTC);

  __shared__ __align__(16) float nA[85 * PITCH];
  __shared__ __align__(16) float xr[80];
  __shared__ __align__(16) float rinv[88];
  __shared__ __align__(16) float u_lds[176];
  __shared__ __align__(16) float rhs_lds[84];
  __shared__ __align__(16) float z_lds[84];
  __shared__ __align__(16) float psumA[240];
  __shared__ __align__(16) float psumB[252];
  __shared__ __align__(16) float psumC[256];
  __shared__ __align__(16) float rkbuf[2][84];
  __shared__ __align__(16) float psq[256];

  const int iB = t % 84, pB = t / 84;   // K row iB, col run [pB*28, +28)   (t<252)
  const int iA = t % 80, pA = t / 80;   // A^T u: col iA, row chunk [pA*32, +32)
  const int rC = t % 85, pC = t / 85;   // A z: row rC, col run pC*28        (t<255)

  if (t < 80) xr[t] = xraw[s * 80 + t];
  if (t < 84) z_lds[t] = 0.f;
  if (t < 176) u_lds[t] = 0.f;

  // ---- load A into LDS + zero pad cols 80..83
  for (int e = t; e < 85 * PITCH; e += 256) {
    int r = e / PITCH, c = e - r * PITCH;
    nA[e] = (c < 80) ? A[r * 80 + c] : 0.f;
  }
  __syncthreads();

  // ---- row norms: 255 threads, 3 partials per row
  if (t < 255) {
    int r = t / 3, p = t - 3 * r;
    int c0 = p * 27;
    int len = (p == 2) ? 26 : 27;
    float acc = 0.f;
    for (int k = 0; k < len; ++k) {
      float v = nA[r * PITCH + c0 + k];
      acc += v * v;
    }
    psq[t] = acc;
  }
  __syncthreads();
  if (t < 85) {
    float n2 = psq[3 * t] + psq[3 * t + 1] + psq[3 * t + 2];
    rinv[t] = 1.0f / fmaxf(sqrtf(n2), 1e-12f);
  }
  __syncthreads();
  for (int e = t; e < 85 * PITCH; e += 256) nA[e] *= rinv[e / PITCH];
  __syncthreads();

  // ---- A^T chunk into packed registers (rows >=85 / t>=240 zero-padded)
  f32x2 at2[16];
  {
    const int r0 = pA * 32;
#pragma unroll
    for (int q = 0; q < 8; ++q) {
      int r = r0 + 4 * q;
      float v0 = (r + 0 < 85) ? nA[(r + 0) * PITCH + iA] : 0.f;
      float v1 = (r + 1 < 85) ? nA[(r + 1) * PITCH + iA] : 0.f;
      float v2 = (r + 2 < 85) ? nA[(r + 2) * PITCH + iA] : 0.f;
      float v3 = (r + 3 < 85) ? nA[(r + 3) * PITCH + iA] : 0.f;
      at2[2 * q + 0] = (f32x2){v0, v1};
      at2[2 * q + 1] = (f32x2){v2, v3};
    }
  }

  // ---- AtA accumulation into kreg (x-rows only; pad cols give 0 for j>=80)
  float kreg[28];   // AtA acc -> K -> -K^{-1}
#pragma unroll
  for (int jj = 0; jj < 28; ++jj) kreg[jj] = 0.f;
  if (t < 252 && iB < 80) {
    for (int r = 0; r < 85; ++r) {
      float ai = nA[r * PITCH + iB];
      const float4* rv = reinterpret_cast<const float4*>(&nA[r * PITCH + pB * 28]);
#pragma unroll
      for (int q = 0; q < 7; ++q) {
        float4 v = rv[q];
        kreg[4 * q + 0] += ai * v.x;
        kreg[4 * q + 1] += ai * v.y;
        kreg[4 * q + 2] += ai * v.z;
        kreg[4 * q + 3] += ai * v.w;
      }
    }
  }

  // ---- assemble K = RHO*G^T G + diag(pdiag + SIGMA) in place
  if (t < 252) {
#pragma unroll
    for (int jj = 0; jj < 28; ++jj) {
      int j = pB * 28 + jj;
      float v;
      if (iB < 80) {
        v = (j < 80)
              ? (RHO_C * kreg[jj] + ((j == iB) ? (RHO_C + 1.0f + SIGMA_C) : 0.f))
              : (-RHO_C * nA[(81 + (j - 80)) * PITCH + iB]);
      } else {
        int ss = iB - 80;
        v = (j < 80)
              ? (-RHO_C * nA[(81 + ss) * PITCH + j])
              : ((j - 80 == ss) ? (2.f * RHO_C + 2.f * PEN_C + SIGMA_C) : 0.f);
      }
      kreg[jj] = v;
    }
  }

  if (t < 252 && iB == 0) {
#pragma unroll
    for (int jj = 0; jj < 28; ++jj) rkbuf[0][pB * 28 + jj] = kreg[jj];
  }
  __syncthreads();

  // ---- SPD sweep (Gauss-Jordan) in registers; final kreg = -K^{-1}
  for (int k = 0; k < NZC; ++k) {
    const float* rk = rkbuf[k & 1];
    const float4* rkv = reinterpret_cast<const float4*>(rk);
    float dinv = 1.0f / rk[k];
    if (t < 252) {
      float t1 = rk[iB] * dinv;
      bool rowk = (iB == k);
      int jfix = k - pB * 28;
      float rkrow[28];
#pragma unroll
      for (int q = 0; q < 7; ++q) {
        float4 v = rkv[pB * 7 + q];
        rkrow[4 * q + 0] = v.x; rkrow[4 * q + 1] = v.y;
        rkrow[4 * q + 2] = v.z; rkrow[4 * q + 3] = v.w;
      }
#pragma unroll
      for (int jj = 0; jj < 28; ++jj) {
        float rkj = rkrow[jj];
        float gen = kreg[jj] - t1 * rkj;
        float val = rowk ? ((jj == jfix) ? -dinv : rkj * dinv)
                         : ((jj == jfix) ? t1 : gen);
        kreg[jj] = val;
      }
      if (k < NZC - 1 && iB == k + 1) {
        float4* wv = reinterpret_cast<float4*>(&rkbuf[(k + 1) & 1][pB * 28]);
#pragma unroll
        for (int q = 0; q < 7; ++q)
          wv[q] = make_float4(kreg[4 * q + 0], kreg[4 * q + 1],
                              kreg[4 * q + 2], kreg[4 * q + 3]);
      }
    }
    __syncthreads();
  }

  // ---- pack -K^{-1} rows into f32x2 pairs (kreg dead afterwards)
  f32x2 kreg2[14];
#pragma unroll
  for (int q = 0; q < 7; ++q) {
    kreg2[2 * q + 0] = (f32x2){kreg[4 * q + 0], kreg[4 * q + 1]};
    kreg2[2 * q + 1] = (f32x2){kreg[4 * q + 2], kreg[4 * q + 3]};
  }

  // ---- per-thread constraint state
  float yor_r = 0.f, h_r = 0.f;
  if (t < MGC) {
    if (t < 85) h_r = bg[s * 85 + t] * rinv[t];
    else if (t < 89) h_r = 0.f;
    else h_r = -lowg[s * 80 + (t - 89)];
  }
  __syncthreads();

  // ---- 200 ADMM iterations
  for (int it = 0; it < ITERS_C; ++it) {
    // phase A: A^T u from packed registers; u as b128 reads (<=2 addrs/wave)
    {
      const float4* ub = reinterpret_cast<const float4*>(&u_lds[pA * 32]);
      f32x2 acc0 = {0.f, 0.f}, acc1 = {0.f, 0.f};
#pragma unroll
      for (int q = 0; q < 8; ++q) {
        float4 uv = ub[q];
        f32x2 ulo = (f32x2){uv.x, uv.y};
        f32x2 uhi = (f32x2){uv.z, uv.w};
        PKFMA(acc0, at2[2 * q + 0], ulo);
        PKFMA(acc1, at2[2 * q + 1], uhi);
      }
      if (t < 240) psumA[pA * 80 + iA] = (acc0.x + acc0.y) + (acc1.x + acc1.y);
    }
    __syncthreads();
    // combine-1: rhs = SIGMA z - q + G^T u
    if (t < 84) {
      float rhsv;
      if (t < 80)
        rhsv = psumA[t] + psumA[80 + t] + psumA[160 + t] + xr[t] + SIGMA_C * z_lds[t] - u_lds[89 + t];
      else {
        int ss = t - 80;
        rhsv = SIGMA_C * z_lds[t] - u_lds[81 + ss] - u_lds[85 + ss];
      }
      rhs_lds[t] = rhsv;
    }
    __syncthreads();
    // phase B: partials of (-K^{-1}) rhs (packed regs, rhs b128 broadcast)
    if (t < 252) {
      const float4* rc = reinterpret_cast<const float4*>(&rhs_lds[pB * 28]);
      f32x2 acc0 = {0.f, 0.f}, acc1 = {0.f, 0.f};
#pragma unroll
      for (int q = 0; q < 7; ++q) {
        float4 rv = rc[q];
        f32x2 rlo = (f32x2){rv.x, rv.y};
        f32x2 rhi = (f32x2){rv.z, rv.w};
        PKFMA(acc0, kreg2[2 * q + 0], rlo);
        PKFMA(acc1, kreg2[2 * q + 1], rhi);
      }
      psumB[pB * 84 + iB] = (acc0.x + acc0.y) + (acc1.x + acc1.y);
    }
    __syncthreads();
    // combine-2: z = K^{-1} rhs (negate the sweep result)
    if (t < 84) z_lds[t] = -(psumB[t] + psumB[84 + t] + psumB[168 + t]);
    __syncthreads();
    // phase C: partials of A z (matrix rows + z both b128, packed FMA)
    if (t < 255) {
      const float4* av = reinterpret_cast<const float4*>(&nA[rC * PITCH + pC * 28]);
      const float4* zv4 = reinterpret_cast<const float4*>(&z_lds[pC * 28]);
      f32x2 acc0 = {0.f, 0.f}, acc1 = {0.f, 0.f};
#pragma unroll
      for (int q = 0; q < 7; ++q) {
        float4 av_ = av[q];
        float4 zv_ = zv4[q];
        f32x2 alo = (f32x2){av_.x, av_.y};
        f32x2 ahi = (f32x2){av_.z, av_.w};
        f32x2 zlo = (f32x2){zv_.x, zv_.y};
        f32x2 zhi = (f32x2){zv_.z, zv_.w};
        PKFMA(acc0, alo, zlo);
        PKFMA(acc1, ahi, zhi);
      }
      psumC[pC * 85 + rC] = (acc0.x + acc0.y) + (acc1.x + acc1.y);
    }
    __syncthreads();
    // update: Gz, v, w=min(v,h), u = RHO(2w - v), yor = v - w
    if (t < MGC) {
      float gz;
      if (t < 85) {
        gz = psumC[t] + psumC[85 + t] + psumC[170 + t];
        if (t >= 81) gz -= z_lds[80 + (t - 81)];
      } else if (t < 89) {
        gz = -z_lds[80 + (t - 85)];
      } else {
        gz = -z_lds[t - 89];
      }
      float v = gz + yor_r;
      float w = fminf(v, h_r);
      u_lds[t] = RHO_C * (2.f * w - v);
      yor_r = v - w;
    }
    __syncthreads();
  }

  if (t < 80) outp[s * 80 + t] = z_lds[t];
}

extern "C" void kernel_launch(void* const* d_in, const int* in_sizes, int n_in,
                              void* d_out, int out_size, void* d_ws, size_t ws_size,
                              hipStream_t stream) {
  const float* xraw = (const float*)d_in[0];
  const float* Ag   = (const float*)d_in[1];
  const float* bg   = (const float*)d_in[2];
  const float* lowg = (const float*)d_in[3];
  float* outp = (float*)d_out;
  const int B = in_sizes[0] / N_ACTC;
  qp_admm_kernel<<<B, 256, 0, stream>>>(xraw, Ag, bg, lowg, outp);
}